// Round 4
// baseline (451.608 us; speedup 1.0000x reference)
//
#include <hip/hip_runtime.h>
#include <hip/hip_bf16.h>

#define TS 64
#define NB 256
#define DI 32
#define NH 10
#define IND 42

struct Cx { float r, i; };
__device__ __forceinline__ Cx cmul(Cx a, Cx b){ return { a.r*b.r - a.i*b.i, a.r*b.i + a.i*b.r }; }
__device__ __forceinline__ Cx csel(Cx a, Cx b, int bit){ return { bit ? b.r : a.r, bit ? b.i : a.i }; }

// signed lane-Walsh: lane L ends with sum_j v_j * (-1)^popcount(L&j)
__device__ __forceinline__ float laneWHT(float v, int lane){
  #pragma unroll
  for (int m = 1; m < 64; m <<= 1) {
    float t = __shfl_xor(v, m);
    v = (lane & m) ? (t - v) : (v + t);
  }
  return v;
}

// Block = 512 threads = 8 waves, one batch element per block.
// Wave (g, Wb): g = circuit (f,i,g,o), Wb = which half of the 1024 amps.
// Amp index j: bits 0..2 = slot (wires 0-2), 3..8 = lane (wires 3-8), 9 = Wb (wire 9).
__global__ __launch_bounds__(512, 1)
void qlstm_kernel(const float* __restrict__ xin,
                  const float* __restrict__ qp,
                  const float* __restrict__ Wf, const float* __restrict__ bfp,
                  const float* __restrict__ Wi, const float* __restrict__ bip,
                  const float* __restrict__ Wg, const float* __restrict__ bgp,
                  const float* __restrict__ Wo, const float* __restrict__ bop,
                  float* __restrict__ out)
{
  __shared__ float lx[TS][DI];
  __shared__ float lW[4][NH][IND];
  __shared__ float lB[4][NH];
  __shared__ __align__(16) float lU1[NH][8];      // layer-1 combined RY*RX*RZ
  __shared__ __align__(16) float lU2[NH][8];      // layer-2 combined
  __shared__ __align__(16) float lv[4][NH][4];    // encoded+layer1 per-wire 2-vectors
  __shared__ __align__(16) float4 ex4[4][2][4][64]; // wire-9 cross-wave exchange (32 KB)
  __shared__ float part[2][4][NH];                // per-wave reduction partials
  __shared__ float lhx[NH];

  const int tid  = threadIdx.x;
  const int b    = blockIdx.x;
  const int wid  = tid >> 6;
  const int g    = wid & 3;
  const int Wb   = wid >> 2;
  const int lane = tid & 63;

  // ---------------- init: stage inputs to LDS ----------------
  for (int i = tid; i < TS*DI; i += 512) {
    int tt = i >> 5, d = i & 31;
    lx[tt][d] = xin[(size_t)tt*(NB*DI) + b*DI + d];
  }
  {
    const float* Wp[4] = { Wf, Wi, Wg, Wo };
    const float* bp[4] = { bfp, bip, bgp, bop };
    for (int gg = 0; gg < 4; gg++) {
      for (int i = tid; i < NH*IND; i += 512) (&lW[gg][0][0])[i] = Wp[gg][i];
      if (tid < NH) lB[gg][tid] = bp[gg][tid];
    }
  }
  if (tid < 20) {  // U = RY(t3)*RX(t2)*RZ(t1) per (layer, wire)
    int l = tid / 10, w = tid % 10;
    float t1 = qp[l*30 + w*3 + 0];
    float t2 = qp[l*30 + w*3 + 1];
    float t3 = qp[l*30 + w*3 + 2];
    float c1 = __cosf(0.5f*t1), s1 = __sinf(0.5f*t1);
    float c2 = __cosf(0.5f*t2), s2 = __sinf(0.5f*t2);
    float c3 = __cosf(0.5f*t3), s3 = __sinf(0.5f*t3);
    float A00r =  c2*c1, A00i = -c2*s1;
    float A01r =  s2*s1, A01i = -s2*c1;
    float A10r = -s2*s1, A10i = -s2*c1;
    float A11r =  c2*c1, A11i =  c2*s1;
    float* dst = (l == 0) ? lU1[w] : lU2[w];
    dst[0] = c3*A00r - s3*A10r; dst[1] = c3*A00i - s3*A10i;
    dst[2] = c3*A01r - s3*A11r; dst[3] = c3*A01i - s3*A11i;
    dst[4] = s3*A00r + c3*A10r; dst[5] = s3*A00i + c3*A10i;
    dst[6] = s3*A01r + c3*A11r; dst[7] = s3*A01i + c3*A11i;
  }
  if (tid < NH) lhx[tid] = 0.f;
  __syncthreads();

  const int l0 = lane&1, l1 = (lane>>1)&1, l2 = (lane>>2)&1,
            l3 = (lane>>3)&1, l4 = (lane>>4)&1, l5 = (lane>>5)&1;

  const int hh = lane & 15;   // matmul output row
  const int qq = lane >> 4;   // matmul k-chunk

  float cstate = 0.f, hval = 0.f;

  for (int t = 0; t < TS; t++) {
    // ---- (a) pre-activations + layer-1 fold (waves Wb==0 only) ----
    if (Wb == 0) {
      float partial = 0.f;
      if (hh < NH) {
        #pragma unroll
        for (int kk = 0; kk < 11; kk++) {
          int k = qq*11 + kk;
          if (k < IND) {
            float cv = (k < DI) ? lx[t][k] : lhx[k - DI];
            partial = fmaf(lW[g][hh][k], cv, partial);
          }
        }
      }
      partial += __shfl_xor(partial, 16);
      partial += __shfl_xor(partial, 32);
      if (qq == 0 && hh < NH) {
        float pre = partial + lB[g][hh];
        float ch = __cosf(0.5f*pre), sh = __sinf(0.5f*pre);
        const float* U = lU1[hh];
        lv[g][hh][0] = U[0]*ch + U[2]*sh;
        lv[g][hh][1] = U[1]*ch + U[3]*sh;
        lv[g][hh][2] = U[4]*ch + U[6]*sh;
        lv[g][hh][3] = U[5]*ch + U[7]*sh;
      }
    }
    __syncthreads();   // #1

    // ---- (b) fetch per-wire 2-vectors ----
    Cx vz[NH], vo[NH];
    #pragma unroll
    for (int w = 0; w < NH; w++) {
      float4 tv = *reinterpret_cast<const float4*>(&lv[g][w][0]);
      vz[w] = { tv.x, tv.y };  vo[w] = { tv.z, tv.w };
    }

    // ---- (c) build 8 amps: amp(j) = prod_w v_w[a_w(j)]
    // a0=s0^Wb, a1=s0^s1^Wb, a2=s1^s2, a3=s2^l0, a4=l0^l1, a5=l1^l2,
    // a6=l2^l3, a7=l3^l4, a8=l4^l5, a9=l5^Wb
    Cx f4 = csel(vz[4], vo[4], l0^l1);
    Cx f5 = csel(vz[5], vo[5], l1^l2);
    Cx f6 = csel(vz[6], vo[6], l2^l3);
    Cx f7 = csel(vz[7], vo[7], l3^l4);
    Cx f8 = csel(vz[8], vo[8], l4^l5);
    Cx f9 = csel(vz[9], vo[9], l5^Wb);
    Cx P  = cmul(cmul(f4, f5), cmul(cmul(f6, f7), cmul(f8, f9)));
    Cx PD[2];  // P * v3[s2^l0]
    PD[0] = cmul(P, csel(vz[3], vo[3], l0));
    PD[1] = cmul(P, csel(vo[3], vz[3], l0));
    Cx Cc[2][2]; // [s1][s2] = v2[s1^s2] * PD[s2]
    #pragma unroll
    for (int s1b = 0; s1b < 2; s1b++)
      #pragma unroll
      for (int s2b = 0; s2b < 2; s2b++)
        Cc[s1b][s2b] = cmul((s1b^s2b) ? vo[2] : vz[2], PD[s2b]);
    Cx Bb[2][2]; // [s0][s1] = v0[s0^Wb] * v1[s0^s1^Wb]
    #pragma unroll
    for (int s0b = 0; s0b < 2; s0b++)
      #pragma unroll
      for (int s1b = 0; s1b < 2; s1b++)
        Bb[s0b][s1b] = cmul((s0b^Wb) ? vo[0] : vz[0], ((s0b^s1b^Wb) ? vo[1] : vz[1]));
    float sre[8], simg[8];
    #pragma unroll
    for (int s = 0; s < 8; s++) {
      int s0b = s&1, s1b = (s>>1)&1, s2b = (s>>2)&1;
      Cx amp = cmul(Bb[s0b][s1b], Cc[s1b][s2b]);
      sre[s] = amp.r; simg[s] = amp.i;
    }

    // ---- (d) layer-2 single-qubit gates ----
    #pragma unroll
    for (int w = 0; w < 3; w++) {          // in-slot wires 0..2
      float4 u0 = *reinterpret_cast<const float4*>(&lU2[w][0]);
      float4 u1 = *reinterpret_cast<const float4*>(&lU2[w][4]);
      #pragma unroll
      for (int s = 0; s < 8; s++) {
        if (!(s & (1 << w))) {
          int s2i = s | (1 << w);
          float ar = sre[s], ai = simg[s], br = sre[s2i], bi = simg[s2i];
          sre[s]    = u0.x*ar - u0.y*ai + u0.z*br - u0.w*bi;
          simg[s]   = u0.x*ai + u0.y*ar + u0.z*bi + u0.w*br;
          sre[s2i]  = u1.x*ar - u1.y*ai + u1.z*br - u1.w*bi;
          simg[s2i] = u1.x*ai + u1.y*ar + u1.z*bi + u1.w*br;
        }
      }
    }
    #pragma unroll
    for (int w = 3; w < 9; w++) {          // cross-lane wires 3..8
      float4 u0 = *reinterpret_cast<const float4*>(&lU2[w][0]);
      float4 u1 = *reinterpret_cast<const float4*>(&lU2[w][4]);
      int m   = (lane >> (w-3)) & 1;
      int msk = 1 << (w-3);
      float car = m ? u1.z : u0.x;
      float cai = m ? u1.w : u0.y;
      float cbr = m ? u1.x : u0.z;
      float cbi = m ? u1.y : u0.w;
      #pragma unroll
      for (int s = 0; s < 8; s++) {
        float pr = __shfl_xor(sre[s],  msk);
        float pi = __shfl_xor(simg[s], msk);
        float nr = car*sre[s]  - cai*simg[s] + cbr*pr - cbi*pi;
        float ni = car*simg[s] + cai*sre[s]  + cbi*pr + cbr*pi;
        sre[s] = nr; simg[s] = ni;
      }
    }
    // wire 9: cross-wave via LDS exchange
    #pragma unroll
    for (int sp = 0; sp < 4; sp++)
      ex4[sp][Wb][g][lane] = make_float4(sre[2*sp], simg[2*sp], sre[2*sp+1], simg[2*sp+1]);
    __syncthreads();   // #2
    {
      float4 u0 = *reinterpret_cast<const float4*>(&lU2[9][0]);
      float4 u1 = *reinterpret_cast<const float4*>(&lU2[9][4]);
      float cOr = Wb ? u1.z : u0.x;   // coef on own amp   (u11 / u00)
      float cOi = Wb ? u1.w : u0.y;
      float cPr = Wb ? u1.x : u0.z;   // coef on partner   (u10 / u01)
      float cPi = Wb ? u1.y : u0.w;
      #pragma unroll
      for (int sp = 0; sp < 4; sp++) {
        float4 pv = ex4[sp][Wb^1][g][lane];
        int s = 2*sp;
        float nr0 = cOr*sre[s]   - cOi*simg[s]   + cPr*pv.x - cPi*pv.y;
        float ni0 = cOr*simg[s]  + cOi*sre[s]    + cPi*pv.x + cPr*pv.y;
        float nr1 = cOr*sre[s+1] - cOi*simg[s+1] + cPr*pv.z - cPi*pv.w;
        float ni1 = cOr*simg[s+1]+ cOi*sre[s+1]  + cPi*pv.z + cPr*pv.w;
        sre[s] = nr0; simg[s] = ni0; sre[s+1] = nr1; simg[s+1] = ni1;
      }
    }

    // ---- (e) probabilities + Walsh reductions ----
    float p[8];
    #pragma unroll
    for (int s = 0; s < 8; s++) p[s] = sre[s]*sre[s] + simg[s]*simg[s];
    #pragma unroll
    for (int bit = 1; bit < 8; bit <<= 1) {   // in-slot signed WHT (3 bits)
      #pragma unroll
      for (int s = 0; s < 8; s++) {
        if (!(s & bit)) {
          float aa = p[s], bb = p[s|bit];
          p[s] = aa + bb; p[s|bit] = aa - bb;
        }
      }
    }
    // slot masks: E0 -> m=6 (s1,s2); E1 -> m=3 (s0,s1); E2..E9 -> m=7
    float w7 = laneWHT(p[7], lane);
    float w6 = laneWHT(p[6], lane);
    float w3 = laneWHT(p[3], lane);
    // lane L of wN holds sum p_N * (-1)^popcount(L & lanebits)
    if (lane == 0)  { part[Wb][g][1] = w3; part[Wb][g][2] = w7; }
    if (lane == 1)  { part[Wb][g][3] = w7; }
    if (lane == 3)  { part[Wb][g][4] = w7; }
    if (lane == 7)  { part[Wb][g][5] = w7; }
    if (lane == 15) { part[Wb][g][6] = w7; }
    if (lane == 31) { part[Wb][g][7] = w7; }
    if (lane == 63) { part[Wb][g][8] = w7; part[Wb][g][9] = w7; part[Wb][g][0] = w6; }
    __syncthreads();   // #3

    // ---- (f,g) combine, activations, LSTM cell (all waves redundantly) ----
    if (lane < NH) {
      float wsgn = (lane == 0 || lane == 9) ? -1.f : 1.f;  // masks containing wire 9
      float Ef = part[0][0][lane] + wsgn*part[1][0][lane];
      float Ei = part[0][1][lane] + wsgn*part[1][1][lane];
      float Eg = part[0][2][lane] + wsgn*part[1][2][lane];
      float Eo = part[0][3][lane] + wsgn*part[1][3][lane];
      float fv = 1.f/(1.f + __expf(-Ef));
      float iv = 1.f/(1.f + __expf(-Ei));
      float eg = __expf(2.f*Eg);  float gv = 1.f - 2.f/(eg + 1.f);
      float ov = 1.f/(1.f + __expf(-Eo));
      cstate = fv*cstate + iv*gv;
      float e = __expf(2.f*cstate);
      hval = ov*(1.f - 2.f/(e + 1.f));
      if (wid == 0) {
        lhx[lane] = hval;
        out[(size_t)t*(NB*NH) + b*NH + lane] = hval;
      }
    }
    __syncthreads();   // #4
  }

  if (wid == 0 && lane < NH) {
    out[(size_t)TS*NB*NH + b*NH + lane]          = hval;
    out[(size_t)TS*NB*NH + NB*NH + b*NH + lane]  = cstate;
  }
}

extern "C" void kernel_launch(void* const* d_in, const int* in_sizes, int n_in,
                              void* d_out, int out_size, void* d_ws, size_t ws_size,
                              hipStream_t stream) {
  (void)in_sizes; (void)n_in; (void)d_ws; (void)ws_size; (void)out_size;
  qlstm_kernel<<<dim3(NB), dim3(512), 0, stream>>>(
      (const float*)d_in[0], (const float*)d_in[1],
      (const float*)d_in[2], (const float*)d_in[3],
      (const float*)d_in[4], (const float*)d_in[5],
      (const float*)d_in[6], (const float*)d_in[7],
      (const float*)d_in[8], (const float*)d_in[9],
      (float*)d_out);
}

// Round 5
// 446.907 us; speedup vs baseline: 1.0105x; 1.0105x over previous
//
#include <hip/hip_runtime.h>

#define TS 64
#define NB 256
#define DI 32
#define NH 10
#define IND 42

struct Cx { float r, i; };
__device__ __forceinline__ Cx cmul(Cx a, Cx b){ return { a.r*b.r - a.i*b.i, a.r*b.i + a.i*b.r }; }
__device__ __forceinline__ Cx csel(Cx a, Cx b, int bit){ return { bit ? b.r : a.r, bit ? b.i : a.i }; }

// xor-lane exchange: ds_swizzle (no VALU addr calc) for masks <32, shfl for 32
template<int MSK>
__device__ __forceinline__ float sx(float v){
  if constexpr (MSK < 32) {
    constexpr int off = (MSK << 10) | 0x1F;   // BitMode: xor=MSK, or=0, and=0x1F
    return __int_as_float(__builtin_amdgcn_ds_swizzle(__float_as_int(v), off));
  } else {
    return __shfl_xor(v, 32);
  }
}

// signed lane-Walsh: lane L ends with sum_j v_j * (-1)^popcount(L&j)
__device__ __forceinline__ float laneWHT(float v, int lane){
  float t;
  t = sx<1>(v);  v = (lane & 1)  ? t - v : v + t;
  t = sx<2>(v);  v = (lane & 2)  ? t - v : v + t;
  t = sx<4>(v);  v = (lane & 4)  ? t - v : v + t;
  t = sx<8>(v);  v = (lane & 8)  ? t - v : v + t;
  t = sx<16>(v); v = (lane & 16) ? t - v : v + t;
  t = sx<32>(v); v = (lane & 32) ? t - v : v + t;
  return v;
}

// cross-lane layer-2 gate on wire W (lane bit W-4), state = 16 complex/lane
template<int W>
__device__ __forceinline__ void xgate(float* sre, float* simg, const float* u, int lane){
  constexpr int MSK = 1 << (W - 4);
  float4 u0 = *reinterpret_cast<const float4*>(u);
  float4 u1 = *reinterpret_cast<const float4*>(u + 4);
  bool m = (lane & MSK) != 0;
  float car = m ? u1.z : u0.x, cai = m ? u1.w : u0.y;   // coef on own amp
  float cbr = m ? u1.x : u0.z, cbi = m ? u1.y : u0.w;   // coef on partner amp
  #pragma unroll
  for (int s = 0; s < 16; s++){
    float pr = sx<MSK>(sre[s]);
    float pi = sx<MSK>(simg[s]);
    float nr = car*sre[s]  - cai*simg[s] + cbr*pr - cbi*pi;
    float ni = car*simg[s] + cai*sre[s]  + cbi*pr + cbr*pi;
    sre[s] = nr; simg[s] = ni;
  }
}

__device__ __forceinline__ float actv(float x, int g){
  if (g == 2) { float e = __expf(2.f*x); return 1.f - 2.f/(e + 1.f); }  // tanh
  return 1.f/(1.f + __expf(-x));                                        // sigmoid
}

// One block per batch element. Wave g (0..3) = circuit g. 1024 amps = 64 lanes x 16 slots.
// Slot bits = wires 0..3, lane bits 0..5 = wires 4..9.
// One barrier per step (lq exchange); lv/lhxw are wave-private LDS (no barrier).
__global__ __launch_bounds__(256, 1)
void qlstm_kernel(const float* __restrict__ xin,
                  const float* __restrict__ qp,
                  const float* __restrict__ Wf, const float* __restrict__ bfp,
                  const float* __restrict__ Wi, const float* __restrict__ bip,
                  const float* __restrict__ Wg, const float* __restrict__ bgp,
                  const float* __restrict__ Wo, const float* __restrict__ bop,
                  float* __restrict__ out)
{
  __shared__ float lx[TS][DI];
  __shared__ float lW[4][NH][IND];
  __shared__ float lB[4][NH];
  __shared__ __align__(16) float lU1[NH][8];      // layer-1 combined RY*RX*RZ
  __shared__ __align__(16) float lU2[NH][8];      // layer-2 combined
  __shared__ __align__(16) float lv[4][NH][4];    // per-wave encoded+layer1 2-vectors
  __shared__ float lq[2][4][NH];                  // double-buffered gate outputs
  __shared__ float lhxw[4][NH];                   // per-wave private h state

  const int tid  = threadIdx.x;
  const int b    = blockIdx.x;
  const int g    = tid >> 6;
  const int lane = tid & 63;

  // ---------------- init: stage inputs to LDS ----------------
  for (int i = tid; i < TS*DI; i += 256) {
    int tt = i >> 5, d = i & 31;
    lx[tt][d] = xin[(size_t)tt*(NB*DI) + b*DI + d];
  }
  {
    const float* Wp[4] = { Wf, Wi, Wg, Wo };
    const float* bp[4] = { bfp, bip, bgp, bop };
    for (int gg = 0; gg < 4; gg++) {
      for (int i = tid; i < NH*IND; i += 256) (&lW[gg][0][0])[i] = Wp[gg][i];
      if (tid < NH) lB[gg][tid] = bp[gg][tid];
    }
  }
  if (tid < 20) {  // U = RY(t3)*RX(t2)*RZ(t1) per (layer, wire)
    int l = tid / 10, w = tid % 10;
    float t1 = qp[l*30 + w*3 + 0];
    float t2 = qp[l*30 + w*3 + 1];
    float t3 = qp[l*30 + w*3 + 2];
    float c1 = __cosf(0.5f*t1), s1 = __sinf(0.5f*t1);
    float c2 = __cosf(0.5f*t2), s2 = __sinf(0.5f*t2);
    float c3 = __cosf(0.5f*t3), s3 = __sinf(0.5f*t3);
    float A00r =  c2*c1, A00i = -c2*s1;
    float A01r =  s2*s1, A01i = -s2*c1;
    float A10r = -s2*s1, A10i = -s2*c1;
    float A11r =  c2*c1, A11i =  c2*s1;
    float* dst = (l == 0) ? lU1[w] : lU2[w];
    dst[0] = c3*A00r - s3*A10r; dst[1] = c3*A00i - s3*A10i;
    dst[2] = c3*A01r - s3*A11r; dst[3] = c3*A01i - s3*A11i;
    dst[4] = s3*A00r + c3*A10r; dst[5] = s3*A00i + c3*A10i;
    dst[6] = s3*A01r + c3*A11r; dst[7] = s3*A01i + c3*A11i;
  }
  if (lane < NH) lhxw[g][lane] = 0.f;
  __syncthreads();

  const int l0 = lane&1, l1 = (lane>>1)&1, l2 = (lane>>2)&1,
            l3 = (lane>>3)&1, l4 = (lane>>4)&1, l5 = (lane>>5)&1;

  const int hh = lane & 15;   // matmul output row
  const int qq = lane >> 4;   // matmul k-chunk

  float cstate = 0.f, hval = 0.f;

  for (int t = 0; t < TS; t++) {
    const int tb = t & 1;
    // ---- (a) pre-activations + layer-1 fold (wave-private: no barrier) ----
    float partial = 0.f;
    if (hh < NH) {
      #pragma unroll
      for (int kk = 0; kk < 11; kk++) {
        int k = qq*11 + kk;
        if (k < IND) {
          float cv = (k < DI) ? lx[t][k] : lhxw[g][k - DI];
          partial = fmaf(lW[g][hh][k], cv, partial);
        }
      }
    }
    partial += sx<16>(partial);
    partial += sx<32>(partial);
    if (qq == 0 && hh < NH) {
      float pre = partial + lB[g][hh];
      float sh, ch;
      __sincosf(0.5f*pre, &sh, &ch);
      const float* U = lU1[hh];
      lv[g][hh][0] = U[0]*ch + U[2]*sh;
      lv[g][hh][1] = U[1]*ch + U[3]*sh;
      lv[g][hh][2] = U[4]*ch + U[6]*sh;
      lv[g][hh][3] = U[5]*ch + U[7]*sh;
    }
    // intra-wave LDS visibility: compiler-inserted lgkmcnt wait suffices

    // ---- (b) fetch per-wire 2-vectors ----
    Cx vz[NH], vo[NH];
    #pragma unroll
    for (int w = 0; w < NH; w++) {
      float4 tv = *reinterpret_cast<const float4*>(&lv[g][w][0]);
      vz[w] = { tv.x, tv.y };  vo[w] = { tv.z, tv.w };
    }

    // ---- (c) build state = ring1( product(v) ) ----
    Cx f5 = csel(vz[5], vo[5], l0^l1);
    Cx f6 = csel(vz[6], vo[6], l1^l2);
    Cx f7 = csel(vz[7], vo[7], l2^l3);
    Cx f8 = csel(vz[8], vo[8], l3^l4);
    Cx f9 = csel(vz[9], vo[9], l4^l5);
    Cx P  = cmul(cmul(f5, f6), cmul(f7, cmul(f8, f9)));
    Cx a4[2]; a4[0] = csel(vz[4], vo[4], l0); a4[1] = csel(vo[4], vz[4], l0);
    Cx u0s[2]; u0s[0] = csel(vz[0], vo[0], l5); u0s[1] = csel(vo[0], vz[0], l5);
    Cx u1s[2]; u1s[0] = csel(vz[1], vo[1], l5); u1s[1] = csel(vo[1], vz[1], l5);
    Cx A[2];  A[0] = cmul(P, a4[0]);  A[1] = cmul(P, a4[1]);
    Cx C[4];
    #pragma unroll
    for (int s1b = 0; s1b < 2; s1b++)
      #pragma unroll
      for (int s0b = 0; s0b < 2; s0b++)
        C[s1b*2+s0b] = cmul(u1s[s0b^s1b], u0s[s0b]);
    Cx AB[8];
    #pragma unroll
    for (int s3b = 0; s3b < 2; s3b++)
      #pragma unroll
      for (int s2b = 0; s2b < 2; s2b++)
        #pragma unroll
        for (int s1b = 0; s1b < 2; s1b++) {
          Cx m23 = cmul((s2b^s3b) ? vo[3] : vz[3], (s1b^s2b) ? vo[2] : vz[2]);
          AB[s3b*4+s2b*2+s1b] = cmul(A[s3b], m23);
        }
    float sre[16], simg[16];
    #pragma unroll
    for (int s = 0; s < 16; s++) {
      int s0b = s&1, s1b = (s>>1)&1, s2b = (s>>2)&1, s3b = (s>>3)&1;
      Cx amp = cmul(AB[s3b*4+s2b*2+s1b], C[s1b*2+s0b]);
      sre[s] = amp.r; simg[s] = amp.i;
    }

    // ---- (d) layer-2 single-qubit gates ----
    #pragma unroll
    for (int w = 0; w < 4; w++) {          // in-slot wires 0..3
      float4 u0 = *reinterpret_cast<const float4*>(&lU2[w][0]);
      float4 u1 = *reinterpret_cast<const float4*>(&lU2[w][4]);
      #pragma unroll
      for (int s = 0; s < 16; s++) {
        if (!(s & (1 << w))) {
          int s2i = s | (1 << w);
          float ar = sre[s], ai = simg[s], br = sre[s2i], bi = simg[s2i];
          sre[s]    = u0.x*ar - u0.y*ai + u0.z*br - u0.w*bi;
          simg[s]   = u0.x*ai + u0.y*ar + u0.z*bi + u0.w*br;
          sre[s2i]  = u1.x*ar - u1.y*ai + u1.z*br - u1.w*bi;
          simg[s2i] = u1.x*ai + u1.y*ar + u1.z*bi + u1.w*br;
        }
      }
    }
    xgate<4>(sre, simg, lU2[4], lane);
    xgate<5>(sre, simg, lU2[5], lane);
    xgate<6>(sre, simg, lU2[6], lane);
    xgate<7>(sre, simg, lU2[7], lane);
    xgate<8>(sre, simg, lU2[8], lane);
    xgate<9>(sre, simg, lU2[9], lane);

    // ---- (e) probabilities + Walsh reductions ----
    float p[16];
    #pragma unroll
    for (int s = 0; s < 16; s++) p[s] = sre[s]*sre[s] + simg[s]*simg[s];
    #pragma unroll
    for (int bit = 1; bit < 16; bit <<= 1) {   // in-slot WHT (slot masks)
      #pragma unroll
      for (int s = 0; s < 16; s++) {
        if (!(s & bit)) {
          float aa = p[s], bb = p[s|bit];
          p[s] = aa + bb; p[s|bit] = aa - bb;
        }
      }
    }
    // lane-WHT the needed slot masks: E0=(14,lm63) E1=(3,0) E2=(7,0)
    // E3..E9=(15, lm=0,1,3,7,15,31,63)
    float w15 = laneWHT(p[15], lane);
    float w14 = laneWHT(p[14], lane);
    float w7  = laneWHT(p[7],  lane);
    float w3  = laneWHT(p[3],  lane);
    float a15 = actv(w15, g), a14 = actv(w14, g), a7 = actv(w7, g), a3 = actv(w3, g);
    if      (lane == 0)  { lq[tb][g][1] = a3; lq[tb][g][2] = a7; lq[tb][g][3] = a15; }
    else if (lane == 1)  { lq[tb][g][4] = a15; }
    else if (lane == 3)  { lq[tb][g][5] = a15; }
    else if (lane == 7)  { lq[tb][g][6] = a15; }
    else if (lane == 15) { lq[tb][g][7] = a15; }
    else if (lane == 31) { lq[tb][g][8] = a15; }
    else if (lane == 63) { lq[tb][g][9] = a15; lq[tb][g][0] = a14; }
    __syncthreads();   // the one barrier: f/i/g/o exchange

    // ---- (f,g) LSTM cell update (all waves redundantly; wave-private h) ----
    if (lane < NH) {
      float fv = lq[tb][0][lane], iv = lq[tb][1][lane],
            gv = lq[tb][2][lane], ov = lq[tb][3][lane];
      cstate = fv*cstate + iv*gv;
      float e = __expf(2.f*cstate);
      hval = ov*(1.f - 2.f/(e + 1.f));
      lhxw[g][lane] = hval;
      if (g == 0) out[(size_t)t*(NB*NH) + b*NH + lane] = hval;
    }
  }

  if (g == 0 && lane < NH) {
    out[(size_t)TS*NB*NH + b*NH + lane]          = hval;
    out[(size_t)TS*NB*NH + NB*NH + b*NH + lane]  = cstate;
  }
}

extern "C" void kernel_launch(void* const* d_in, const int* in_sizes, int n_in,
                              void* d_out, int out_size, void* d_ws, size_t ws_size,
                              hipStream_t stream) {
  (void)in_sizes; (void)n_in; (void)d_ws; (void)ws_size; (void)out_size;
  qlstm_kernel<<<dim3(NB), dim3(256), 0, stream>>>(
      (const float*)d_in[0], (const float*)d_in[1],
      (const float*)d_in[2], (const float*)d_in[3],
      (const float*)d_in[4], (const float*)d_in[5],
      (const float*)d_in[6], (const float*)d_in[7],
      (const float*)d_in[8], (const float*)d_in[9],
      (float*)d_out);
}

// Round 6
// 416.449 us; speedup vs baseline: 1.0844x; 1.0731x over previous
//
#include <hip/hip_runtime.h>

#define TS 64
#define NB 256
#define DI 32
#define NH 10
#define IND 42

struct Cx { float r, i; };
__device__ __forceinline__ Cx cmul(Cx a, Cx b){ return { a.r*b.r - a.i*b.i, a.r*b.i + a.i*b.r }; }
__device__ __forceinline__ Cx csel(Cx a, Cx b, int bit){ return { bit ? b.r : a.r, bit ? b.i : a.i }; }

// xor-lane exchange: ds_swizzle (no VALU addr calc) for masks <32, bpermute for 32
template<int MSK>
__device__ __forceinline__ float sx(float v){
  if constexpr (MSK < 32) {
    constexpr int off = (MSK << 10) | 0x1F;   // BitMode: xor=MSK, or=0, and=0x1F
    return __int_as_float(__builtin_amdgcn_ds_swizzle(__float_as_int(v), off));
  } else {
    return __shfl_xor(v, 32);
  }
}

__device__ __forceinline__ float sigm(float x){ return 1.f/(1.f + __expf(-x)); }
__device__ __forceinline__ float tanhr(float x){ float e = __expf(2.f*x); return 1.f - 2.f/(e + 1.f); }

// one WHT butterfly stage for 4 values in lock-step: 4 swizzles issue together -> 1 wait
template<int MSK>
__device__ __forceinline__ void wht4s(float& a, float& b, float& c, float& d, int lane){
  float ta = sx<MSK>(a), tb = sx<MSK>(b), tc = sx<MSK>(c), td = sx<MSK>(d);
  bool m = (lane & MSK) != 0;
  a = m ? ta - a : a + ta;
  b = m ? tb - b : b + tb;
  c = m ? tc - c : c + tc;
  d = m ? td - d : d + td;
}

// cross-lane layer-2 gate on wire W (lane bit W-4), state = 16 complex/lane.
// BATCHED: all 32 exchanges gathered into pr/pi before any compute (one lgkm wait).
template<int W>
__device__ __forceinline__ void xgate(float* sre, float* simg, const float* u, int lane){
  constexpr int MSK = 1 << (W - 4);
  float pr[16], pi[16];
  #pragma unroll
  for (int s = 0; s < 16; s++) pr[s] = sx<MSK>(sre[s]);
  #pragma unroll
  for (int s = 0; s < 16; s++) pi[s] = sx<MSK>(simg[s]);
  float4 u0 = *reinterpret_cast<const float4*>(u);
  float4 u1 = *reinterpret_cast<const float4*>(u + 4);
  bool m = (lane & MSK) != 0;
  float car = m ? u1.z : u0.x, cai = m ? u1.w : u0.y;   // coef on own amp
  float cbr = m ? u1.x : u0.z, cbi = m ? u1.y : u0.w;   // coef on partner amp
  #pragma unroll
  for (int s = 0; s < 16; s++){
    float nr = car*sre[s]  - cai*simg[s] + cbr*pr[s] - cbi*pi[s];
    float ni = car*simg[s] + cai*sre[s]  + cbi*pr[s] + cbr*pi[s];
    sre[s] = nr; simg[s] = ni;
  }
}

// One block per batch element. Wave g (0..3) = circuit g. 1024 amps = 64 lanes x 16 slots.
// Slot bits = wires 0..3, lane bits 0..5 = wires 4..9.
// One barrier per step (raw-E exchange); lv/lhxw are wave-private LDS (no barrier).
__global__ __launch_bounds__(256, 1)
void qlstm_kernel(const float* __restrict__ xin,
                  const float* __restrict__ qp,
                  const float* __restrict__ Wf, const float* __restrict__ bfp,
                  const float* __restrict__ Wi, const float* __restrict__ bip,
                  const float* __restrict__ Wg, const float* __restrict__ bgp,
                  const float* __restrict__ Wo, const float* __restrict__ bop,
                  float* __restrict__ out)
{
  __shared__ float lx[TS][DI];
  __shared__ float lW[4][NH][IND];
  __shared__ float lB[4][NH];
  __shared__ __align__(16) float lU1[NH][8];      // layer-1 combined RY*RX*RZ
  __shared__ __align__(16) float lU2[NH][8];      // layer-2 combined
  __shared__ __align__(16) float lv[4][NH][4];    // per-wave encoded+layer1 2-vectors
  __shared__ float lq[2][4][NH];                  // double-buffered raw E exchange
  __shared__ float lhxw[4][NH];                   // per-wave private h state

  const int tid  = threadIdx.x;
  const int b    = blockIdx.x;
  const int g    = tid >> 6;
  const int lane = tid & 63;

  // ---------------- init: stage inputs to LDS ----------------
  for (int i = tid; i < TS*DI; i += 256) {
    int tt = i >> 5, d = i & 31;
    lx[tt][d] = xin[(size_t)tt*(NB*DI) + b*DI + d];
  }
  {
    const float* Wp[4] = { Wf, Wi, Wg, Wo };
    const float* bp[4] = { bfp, bip, bgp, bop };
    for (int gg = 0; gg < 4; gg++) {
      for (int i = tid; i < NH*IND; i += 256) (&lW[gg][0][0])[i] = Wp[gg][i];
      if (tid < NH) lB[gg][tid] = bp[gg][tid];
    }
  }
  if (tid < 20) {  // U = RY(t3)*RX(t2)*RZ(t1) per (layer, wire)
    int l = tid / 10, w = tid % 10;
    float t1 = qp[l*30 + w*3 + 0];
    float t2 = qp[l*30 + w*3 + 1];
    float t3 = qp[l*30 + w*3 + 2];
    float c1 = __cosf(0.5f*t1), s1 = __sinf(0.5f*t1);
    float c2 = __cosf(0.5f*t2), s2 = __sinf(0.5f*t2);
    float c3 = __cosf(0.5f*t3), s3 = __sinf(0.5f*t3);
    float A00r =  c2*c1, A00i = -c2*s1;
    float A01r =  s2*s1, A01i = -s2*c1;
    float A10r = -s2*s1, A10i = -s2*c1;
    float A11r =  c2*c1, A11i =  c2*s1;
    float* dst = (l == 0) ? lU1[w] : lU2[w];
    dst[0] = c3*A00r - s3*A10r; dst[1] = c3*A00i - s3*A10i;
    dst[2] = c3*A01r - s3*A11r; dst[3] = c3*A01i - s3*A11i;
    dst[4] = s3*A00r + c3*A10r; dst[5] = s3*A00i + c3*A10i;
    dst[6] = s3*A01r + c3*A11r; dst[7] = s3*A01i + c3*A11i;
  }
  if (lane < NH) lhxw[g][lane] = 0.f;
  __syncthreads();

  const int l0 = lane&1, l1 = (lane>>1)&1, l2 = (lane>>2)&1,
            l3 = (lane>>3)&1, l4 = (lane>>4)&1, l5 = (lane>>5)&1;

  const int hh = lane & 15;   // matmul output row
  const int qq = lane >> 4;   // matmul k-chunk

  float cstate = 0.f, hval = 0.f;

  for (int t = 0; t < TS; t++) {
    const int tb = t & 1;
    // ---- (a) pre-activations + layer-1 fold (wave-private: no barrier) ----
    float partial = 0.f;
    if (hh < NH) {
      #pragma unroll
      for (int kk = 0; kk < 11; kk++) {
        int k = qq*11 + kk;
        if (k < IND) {
          float cv = (k < DI) ? lx[t][k] : lhxw[g][k - DI];
          partial = fmaf(lW[g][hh][k], cv, partial);
        }
      }
    }
    partial += sx<16>(partial);
    partial += sx<32>(partial);
    if (qq == 0 && hh < NH) {
      float pre = partial + lB[g][hh];
      float sh, ch;
      __sincosf(0.5f*pre, &sh, &ch);
      const float* U = lU1[hh];
      lv[g][hh][0] = U[0]*ch + U[2]*sh;
      lv[g][hh][1] = U[1]*ch + U[3]*sh;
      lv[g][hh][2] = U[4]*ch + U[6]*sh;
      lv[g][hh][3] = U[5]*ch + U[7]*sh;
    }
    // intra-wave LDS visibility: compiler-inserted lgkmcnt wait suffices

    // ---- (b) fetch per-wire 2-vectors ----
    Cx vz[NH], vo[NH];
    #pragma unroll
    for (int w = 0; w < NH; w++) {
      float4 tv = *reinterpret_cast<const float4*>(&lv[g][w][0]);
      vz[w] = { tv.x, tv.y };  vo[w] = { tv.z, tv.w };
    }

    // ---- (c) build state = ring1( product(v) ) ----
    Cx f5 = csel(vz[5], vo[5], l0^l1);
    Cx f6 = csel(vz[6], vo[6], l1^l2);
    Cx f7 = csel(vz[7], vo[7], l2^l3);
    Cx f8 = csel(vz[8], vo[8], l3^l4);
    Cx f9 = csel(vz[9], vo[9], l4^l5);
    Cx P  = cmul(cmul(f5, f6), cmul(f7, cmul(f8, f9)));
    Cx a4[2]; a4[0] = csel(vz[4], vo[4], l0); a4[1] = csel(vo[4], vz[4], l0);
    Cx u0s[2]; u0s[0] = csel(vz[0], vo[0], l5); u0s[1] = csel(vo[0], vz[0], l5);
    Cx u1s[2]; u1s[0] = csel(vz[1], vo[1], l5); u1s[1] = csel(vo[1], vz[1], l5);
    Cx A[2];  A[0] = cmul(P, a4[0]);  A[1] = cmul(P, a4[1]);
    Cx C[4];
    #pragma unroll
    for (int s1b = 0; s1b < 2; s1b++)
      #pragma unroll
      for (int s0b = 0; s0b < 2; s0b++)
        C[s1b*2+s0b] = cmul(u1s[s0b^s1b], u0s[s0b]);
    Cx AB[8];
    #pragma unroll
    for (int s3b = 0; s3b < 2; s3b++)
      #pragma unroll
      for (int s2b = 0; s2b < 2; s2b++)
        #pragma unroll
        for (int s1b = 0; s1b < 2; s1b++) {
          Cx m23 = cmul((s2b^s3b) ? vo[3] : vz[3], (s1b^s2b) ? vo[2] : vz[2]);
          AB[s3b*4+s2b*2+s1b] = cmul(A[s3b], m23);
        }
    float sre[16], simg[16];
    #pragma unroll
    for (int s = 0; s < 16; s++) {
      int s0b = s&1, s1b = (s>>1)&1, s2b = (s>>2)&1, s3b = (s>>3)&1;
      Cx amp = cmul(AB[s3b*4+s2b*2+s1b], C[s1b*2+s0b]);
      sre[s] = amp.r; simg[s] = amp.i;
    }

    // ---- (d) layer-2 single-qubit gates ----
    #pragma unroll
    for (int w = 0; w < 4; w++) {          // in-slot wires 0..3 (pure VALU)
      float4 u0 = *reinterpret_cast<const float4*>(&lU2[w][0]);
      float4 u1 = *reinterpret_cast<const float4*>(&lU2[w][4]);
      #pragma unroll
      for (int s = 0; s < 16; s++) {
        if (!(s & (1 << w))) {
          int s2i = s | (1 << w);
          float ar = sre[s], ai = simg[s], br = sre[s2i], bi = simg[s2i];
          sre[s]    = u0.x*ar - u0.y*ai + u0.z*br - u0.w*bi;
          simg[s]   = u0.x*ai + u0.y*ar + u0.z*bi + u0.w*br;
          sre[s2i]  = u1.x*ar - u1.y*ai + u1.z*br - u1.w*bi;
          simg[s2i] = u1.x*ai + u1.y*ar + u1.z*bi + u1.w*br;
        }
      }
    }
    xgate<4>(sre, simg, lU2[4], lane);
    xgate<5>(sre, simg, lU2[5], lane);
    xgate<6>(sre, simg, lU2[6], lane);
    xgate<7>(sre, simg, lU2[7], lane);
    xgate<8>(sre, simg, lU2[8], lane);
    xgate<9>(sre, simg, lU2[9], lane);

    // ---- (e) probabilities + Walsh reductions ----
    float p[16];
    #pragma unroll
    for (int s = 0; s < 16; s++) p[s] = sre[s]*sre[s] + simg[s]*simg[s];
    #pragma unroll
    for (int bit = 1; bit < 16; bit <<= 1) {   // in-slot WHT (slot masks)
      #pragma unroll
      for (int s = 0; s < 16; s++) {
        if (!(s & bit)) {
          float aa = p[s], bb = p[s|bit];
          p[s] = aa + bb; p[s|bit] = aa - bb;
        }
      }
    }
    // lane-WHT 4 slot-masks in lock-step: E0=(14,lm63) E1=(3,0) E2=(7,0)
    // E3..E9=(15, lm=0,1,3,7,15,31,63)
    float w15 = p[15], w14 = p[14], w7 = p[7], w3 = p[3];
    wht4s<1> (w15, w14, w7, w3, lane);
    wht4s<2> (w15, w14, w7, w3, lane);
    wht4s<4> (w15, w14, w7, w3, lane);
    wht4s<8> (w15, w14, w7, w3, lane);
    wht4s<16>(w15, w14, w7, w3, lane);
    wht4s<32>(w15, w14, w7, w3, lane);
    if      (lane == 0)  { lq[tb][g][1] = w3; lq[tb][g][2] = w7; lq[tb][g][3] = w15; }
    else if (lane == 1)  { lq[tb][g][4] = w15; }
    else if (lane == 3)  { lq[tb][g][5] = w15; }
    else if (lane == 7)  { lq[tb][g][6] = w15; }
    else if (lane == 15) { lq[tb][g][7] = w15; }
    else if (lane == 31) { lq[tb][g][8] = w15; }
    else if (lane == 63) { lq[tb][g][9] = w15; lq[tb][g][0] = w14; }
    __syncthreads();   // the one barrier: raw-E exchange

    // ---- (f,g) activations + LSTM cell (all waves redundantly; wave-private h) ----
    if (lane < NH) {
      float fv = sigm (lq[tb][0][lane]);
      float iv = sigm (lq[tb][1][lane]);
      float gv = tanhr(lq[tb][2][lane]);
      float ov = sigm (lq[tb][3][lane]);
      cstate = fv*cstate + iv*gv;
      hval = ov*tanhr(cstate);
      lhxw[g][lane] = hval;
      if (g == 0) out[(size_t)t*(NB*NH) + b*NH + lane] = hval;
    }
  }

  if (g == 0 && lane < NH) {
    out[(size_t)TS*NB*NH + b*NH + lane]          = hval;
    out[(size_t)TS*NB*NH + NB*NH + b*NH + lane]  = cstate;
  }
}

extern "C" void kernel_launch(void* const* d_in, const int* in_sizes, int n_in,
                              void* d_out, int out_size, void* d_ws, size_t ws_size,
                              hipStream_t stream) {
  (void)in_sizes; (void)n_in; (void)d_ws; (void)ws_size; (void)out_size;
  qlstm_kernel<<<dim3(NB), dim3(256), 0, stream>>>(
      (const float*)d_in[0], (const float*)d_in[1],
      (const float*)d_in[2], (const float*)d_in[3],
      (const float*)d_in[4], (const float*)d_in[5],
      (const float*)d_in[6], (const float*)d_in[7],
      (const float*)d_in[8], (const float*)d_in[9],
      (float*)d_out);
}

// Round 7
// 384.039 us; speedup vs baseline: 1.1759x; 1.0844x over previous
//
#include <hip/hip_runtime.h>

#define TS 64
#define NB 256
#define DI 32
#define NH 10
#define IND 42

struct Cx { float r, i; };
__device__ __forceinline__ Cx cmul(Cx a, Cx b){ return { a.r*b.r - a.i*b.i, a.r*b.i + a.i*b.r }; }
__device__ __forceinline__ Cx csel(Cx a, Cx b, int bit){ return { bit ? b.r : a.r, bit ? b.i : a.i }; }

// xor-lane exchange: ds_swizzle for masks <32, shfl for 32
template<int MSK>
__device__ __forceinline__ float sx(float v){
  if constexpr (MSK < 32) {
    constexpr int off = (MSK << 10) | 0x1F;   // BitMode: xor=MSK, or=0, and=0x1F
    return __int_as_float(__builtin_amdgcn_ds_swizzle(__float_as_int(v), off));
  } else {
    return __shfl_xor(v, 32);
  }
}

__device__ __forceinline__ float sigm(float x){ return 1.f/(1.f + __expf(-x)); }
__device__ __forceinline__ float tanhr(float x){ float e = __expf(2.f*x); return 1.f - 2.f/(e + 1.f); }

// one WHT butterfly stage for 4 values in lock-step
template<int MSK>
__device__ __forceinline__ void wht4s(float& a, float& b, float& c, float& d, int lane){
  float ta = sx<MSK>(a), tb = sx<MSK>(b), tc = sx<MSK>(c), td = sx<MSK>(d);
  bool m = (lane & MSK) != 0;
  a = m ? ta - a : a + ta;
  b = m ? tb - b : b + tb;
  c = m ? tc - c : c + tc;
  d = m ? td - d : d + td;
}

// cross-lane layer-2 gate, coefficients pre-selected per lane (registers)
template<int MSK>
__device__ __forceinline__ void xgate2(float* sre, float* simg,
                                       float car, float cai, float cbr, float cbi){
  float pr[16], pi[16];
  #pragma unroll
  for (int s = 0; s < 16; s++) pr[s] = sx<MSK>(sre[s]);
  #pragma unroll
  for (int s = 0; s < 16; s++) pi[s] = sx<MSK>(simg[s]);
  #pragma unroll
  for (int s = 0; s < 16; s++){
    float nr = car*sre[s]  - cai*simg[s] + cbr*pr[s] - cbi*pi[s];
    float ni = car*simg[s] + cai*sre[s]  + cbi*pr[s] + cbr*pi[s];
    sre[s] = nr; simg[s] = ni;
  }
}

// combined U = RY(t3)*RX(t2)*RZ(t1) -> 8 floats (row0 r/i pairs, row1 r/i pairs)
__device__ __forceinline__ void mkU(float t1, float t2, float t3, float* dst){
  float c1 = __cosf(0.5f*t1), s1 = __sinf(0.5f*t1);
  float c2 = __cosf(0.5f*t2), s2 = __sinf(0.5f*t2);
  float c3 = __cosf(0.5f*t3), s3 = __sinf(0.5f*t3);
  float A00r =  c2*c1, A00i = -c2*s1;
  float A01r =  s2*s1, A01i = -s2*c1;
  float A10r = -s2*s1, A10i = -s2*c1;
  float A11r =  c2*c1, A11i =  c2*s1;
  dst[0] = c3*A00r - s3*A10r; dst[1] = c3*A00i - s3*A10i;
  dst[2] = c3*A01r - s3*A11r; dst[3] = c3*A01i - s3*A11i;
  dst[4] = s3*A00r + c3*A10r; dst[5] = s3*A00i + c3*A10i;
  dst[6] = s3*A01r + c3*A11r; dst[7] = s3*A01i + c3*A11i;
}

// One block per batch element. Wave g (0..3) = circuit g. 1024 amps = 64 lanes x 16 slots.
// Slot bits = wires 0..3, lane bits 0..5 = wires 4..9. One barrier per step.
// Occupancy is grid-limited (1 wave/SIMD) -> spend VGPRs freely: weights, gate
// matrices, xgate coefficients all register-resident; x software-prefetched.
__global__ __launch_bounds__(256, 1)
void qlstm_kernel(const float* __restrict__ xin,
                  const float* __restrict__ qp,
                  const float* __restrict__ Wf, const float* __restrict__ bfp,
                  const float* __restrict__ Wi, const float* __restrict__ bip,
                  const float* __restrict__ Wg, const float* __restrict__ bgp,
                  const float* __restrict__ Wo, const float* __restrict__ bop,
                  float* __restrict__ out)
{
  __shared__ __align__(16) float lv[4][NH][4];    // per-wave encoded+layer1 2-vectors
  __shared__ float lq[2][4][NH];                  // double-buffered raw E exchange
  __shared__ float lhxw[4][NH];                   // per-wave private h state
  __shared__ __align__(16) float lU2s[NH][8];     // layer-2 matrices (staging)

  const int tid  = threadIdx.x;
  const int b    = blockIdx.x;
  const int g    = tid >> 6;
  const int lane = tid & 63;
  const int hrow = (lane < NH) ? lane : 0;

  // ---- init: register-resident weights + gate matrices ----
  const float* Wsel = (g==0) ? Wf : (g==1) ? Wi : (g==2) ? Wg : Wo;
  const float* bsel = (g==0) ? bfp : (g==1) ? bip : (g==2) ? bgp : bop;
  float wreg[IND];
  #pragma unroll
  for (int k = 0; k < IND; k++) wreg[k] = Wsel[hrow*IND + k];
  const float breg = bsel[hrow];

  float U1[8];   // layer-1 combined matrix for wire == hrow
  mkU(qp[hrow*3+0], qp[hrow*3+1], qp[hrow*3+2], U1);

  if (tid < NH) {
    float u[8];
    mkU(qp[30 + tid*3 + 0], qp[30 + tid*3 + 1], qp[30 + tid*3 + 2], u);
    #pragma unroll
    for (int i = 0; i < 8; i++) lU2s[tid][i] = u[i];
  }
  if (lane < NH) lhxw[g][lane] = 0.f;
  __syncthreads();

  // layer-2 matrices -> registers (broadcast reads, once)
  float4 gql[4], gqh[4];
  #pragma unroll
  for (int w = 0; w < 4; w++) {
    gql[w] = *reinterpret_cast<const float4*>(&lU2s[w][0]);
    gqh[w] = *reinterpret_cast<const float4*>(&lU2s[w][4]);
  }
  float car[6], cai[6], cbr[6], cbi[6];   // pre-selected xgate coefficients
  #pragma unroll
  for (int j = 0; j < 6; j++) {
    float4 lo = *reinterpret_cast<const float4*>(&lU2s[4+j][0]);
    float4 hi = *reinterpret_cast<const float4*>(&lU2s[4+j][4]);
    bool m = (lane >> j) & 1;
    car[j] = m ? hi.z : lo.x;  cai[j] = m ? hi.w : lo.y;
    cbr[j] = m ? hi.x : lo.z;  cbi[j] = m ? hi.y : lo.w;
  }

  const int l0 = lane&1, l1 = (lane>>1)&1, l2 = (lane>>2)&1,
            l3 = (lane>>3)&1, l4 = (lane>>4)&1, l5 = (lane>>5)&1;

  // ---- x software pipeline: xf holds x[t+1]; wxc = W.x for current t ----
  const float* xb = xin + (size_t)b*DI;
  float4 xf[8];
  #pragma unroll
  for (int r = 0; r < 8; r++) xf[r] = *reinterpret_cast<const float4*>(xb + r*4);
  float wxc = 0.f;
  #pragma unroll
  for (int r = 0; r < 8; r++) {
    wxc = fmaf(wreg[4*r+0], xf[r].x, wxc);
    wxc = fmaf(wreg[4*r+1], xf[r].y, wxc);
    wxc = fmaf(wreg[4*r+2], xf[r].z, wxc);
    wxc = fmaf(wreg[4*r+3], xf[r].w, wxc);
  }
  #pragma unroll
  for (int r = 0; r < 8; r++)
    xf[r] = *reinterpret_cast<const float4*>(xb + (size_t)1*NB*DI + r*4);

  float cstate = 0.f, hval = 0.f;

  for (int t = 0; t < TS; t++) {
    const int tb = t & 1;
    // ---- (a) pre-activation: registers + 10 LDS broadcast reads ----
    float pre = wxc + breg;
    #pragma unroll
    for (int j = 0; j < NH; j++) pre = fmaf(wreg[DI+j], lhxw[g][j], pre);
    float sh, ch;
    __sincosf(0.5f*pre, &sh, &ch);
    if (lane < NH) {
      *reinterpret_cast<float4*>(&lv[g][lane][0]) =
        make_float4(U1[0]*ch + U1[2]*sh, U1[1]*ch + U1[3]*sh,
                    U1[4]*ch + U1[6]*sh, U1[5]*ch + U1[7]*sh);
    }

    // ---- pipeline advance (off critical path): Wx for t+1, load x for t+2 ----
    float wxn = 0.f;
    #pragma unroll
    for (int r = 0; r < 8; r++) {
      wxn = fmaf(wreg[4*r+0], xf[r].x, wxn);
      wxn = fmaf(wreg[4*r+1], xf[r].y, wxn);
      wxn = fmaf(wreg[4*r+2], xf[r].z, wxn);
      wxn = fmaf(wreg[4*r+3], xf[r].w, wxn);
    }
    {
      int tn = (t + 2 < TS) ? t + 2 : 0;
      #pragma unroll
      for (int r = 0; r < 8; r++)
        xf[r] = *reinterpret_cast<const float4*>(xb + (size_t)tn*NB*DI + r*4);
    }

    // ---- (b) fetch per-wire 2-vectors (wave-private LDS broadcast) ----
    Cx vz[NH], vo[NH];
    #pragma unroll
    for (int w = 0; w < NH; w++) {
      float4 tv = *reinterpret_cast<const float4*>(&lv[g][w][0]);
      vz[w] = { tv.x, tv.y };  vo[w] = { tv.z, tv.w };
    }

    // ---- (c) build state = ring1( product(v) ) ----
    Cx f5 = csel(vz[5], vo[5], l0^l1);
    Cx f6 = csel(vz[6], vo[6], l1^l2);
    Cx f7 = csel(vz[7], vo[7], l2^l3);
    Cx f8 = csel(vz[8], vo[8], l3^l4);
    Cx f9 = csel(vz[9], vo[9], l4^l5);
    Cx P  = cmul(cmul(f5, f6), cmul(f7, cmul(f8, f9)));
    Cx a4[2]; a4[0] = csel(vz[4], vo[4], l0); a4[1] = csel(vo[4], vz[4], l0);
    Cx u0s[2]; u0s[0] = csel(vz[0], vo[0], l5); u0s[1] = csel(vo[0], vz[0], l5);
    Cx u1s[2]; u1s[0] = csel(vz[1], vo[1], l5); u1s[1] = csel(vo[1], vz[1], l5);
    Cx A[2];  A[0] = cmul(P, a4[0]);  A[1] = cmul(P, a4[1]);
    Cx C[4];
    #pragma unroll
    for (int s1b = 0; s1b < 2; s1b++)
      #pragma unroll
      for (int s0b = 0; s0b < 2; s0b++)
        C[s1b*2+s0b] = cmul(u1s[s0b^s1b], u0s[s0b]);
    Cx AB[8];
    #pragma unroll
    for (int s3b = 0; s3b < 2; s3b++)
      #pragma unroll
      for (int s2b = 0; s2b < 2; s2b++)
        #pragma unroll
        for (int s1b = 0; s1b < 2; s1b++) {
          Cx m23 = cmul((s2b^s3b) ? vo[3] : vz[3], (s1b^s2b) ? vo[2] : vz[2]);
          AB[s3b*4+s2b*2+s1b] = cmul(A[s3b], m23);
        }
    float sre[16], simg[16];
    #pragma unroll
    for (int s = 0; s < 16; s++) {
      int s0b = s&1, s1b = (s>>1)&1, s2b = (s>>2)&1, s3b = (s>>3)&1;
      Cx amp = cmul(AB[s3b*4+s2b*2+s1b], C[s1b*2+s0b]);
      sre[s] = amp.r; simg[s] = amp.i;
    }

    // ---- (d) layer-2 single-qubit gates (register coefficients) ----
    #pragma unroll
    for (int w = 0; w < 4; w++) {          // in-slot wires 0..3 (pure VALU)
      float4 u0 = gql[w], u1 = gqh[w];
      #pragma unroll
      for (int s = 0; s < 16; s++) {
        if (!(s & (1 << w))) {
          int s2i = s | (1 << w);
          float ar = sre[s], ai = simg[s], br = sre[s2i], bi = simg[s2i];
          sre[s]    = u0.x*ar - u0.y*ai + u0.z*br - u0.w*bi;
          simg[s]   = u0.x*ai + u0.y*ar + u0.z*bi + u0.w*br;
          sre[s2i]  = u1.x*ar - u1.y*ai + u1.z*br - u1.w*bi;
          simg[s2i] = u1.x*ai + u1.y*ar + u1.z*bi + u1.w*br;
        }
      }
    }
    xgate2<1> (sre, simg, car[0], cai[0], cbr[0], cbi[0]);
    xgate2<2> (sre, simg, car[1], cai[1], cbr[1], cbi[1]);
    xgate2<4> (sre, simg, car[2], cai[2], cbr[2], cbi[2]);
    xgate2<8> (sre, simg, car[3], cai[3], cbr[3], cbi[3]);
    xgate2<16>(sre, simg, car[4], cai[4], cbr[4], cbi[4]);
    xgate2<32>(sre, simg, car[5], cai[5], cbr[5], cbi[5]);

    // ---- (e) probabilities + Walsh reductions ----
    float p[16];
    #pragma unroll
    for (int s = 0; s < 16; s++) p[s] = sre[s]*sre[s] + simg[s]*simg[s];
    #pragma unroll
    for (int bit = 1; bit < 16; bit <<= 1) {
      #pragma unroll
      for (int s = 0; s < 16; s++) {
        if (!(s & bit)) {
          float aa = p[s], bb = p[s|bit];
          p[s] = aa + bb; p[s|bit] = aa - bb;
        }
      }
    }
    // E0=(14,lm63) E1=(3,0) E2=(7,0) E3..E9=(15, lm=0,1,3,7,15,31,63)
    float w15 = p[15], w14 = p[14], w7 = p[7], w3 = p[3];
    wht4s<1> (w15, w14, w7, w3, lane);
    wht4s<2> (w15, w14, w7, w3, lane);
    wht4s<4> (w15, w14, w7, w3, lane);
    wht4s<8> (w15, w14, w7, w3, lane);
    wht4s<16>(w15, w14, w7, w3, lane);
    wht4s<32>(w15, w14, w7, w3, lane);
    if      (lane == 0)  { lq[tb][g][1] = w3; lq[tb][g][2] = w7; lq[tb][g][3] = w15; }
    else if (lane == 1)  { lq[tb][g][4] = w15; }
    else if (lane == 3)  { lq[tb][g][5] = w15; }
    else if (lane == 7)  { lq[tb][g][6] = w15; }
    else if (lane == 15) { lq[tb][g][7] = w15; }
    else if (lane == 31) { lq[tb][g][8] = w15; }
    else if (lane == 63) { lq[tb][g][9] = w15; lq[tb][g][0] = w14; }
    __syncthreads();   // the one barrier: raw-E exchange

    // ---- (f) activations + LSTM cell (lanes 0..9, per wave redundantly) ----
    if (lane < NH) {
      float fv = sigm (lq[tb][0][lane]);
      float iv = sigm (lq[tb][1][lane]);
      float gv = tanhr(lq[tb][2][lane]);
      float ov = sigm (lq[tb][3][lane]);
      cstate = fv*cstate + iv*gv;
      hval = ov*tanhr(cstate);
      lhxw[g][lane] = hval;
      if (g == 0) out[(size_t)t*(NB*NH) + b*NH + lane] = hval;
    }
    wxc = wxn;
  }

  if (g == 0 && lane < NH) {
    out[(size_t)TS*NB*NH + b*NH + lane]          = hval;
    out[(size_t)TS*NB*NH + NB*NH + b*NH + lane]  = cstate;
  }
}

extern "C" void kernel_launch(void* const* d_in, const int* in_sizes, int n_in,
                              void* d_out, int out_size, void* d_ws, size_t ws_size,
                              hipStream_t stream) {
  (void)in_sizes; (void)n_in; (void)d_ws; (void)ws_size; (void)out_size;
  qlstm_kernel<<<dim3(NB), dim3(256), 0, stream>>>(
      (const float*)d_in[0], (const float*)d_in[1],
      (const float*)d_in[2], (const float*)d_in[3],
      (const float*)d_in[4], (const float*)d_in[5],
      (const float*)d_in[6], (const float*)d_in[7],
      (const float*)d_in[8], (const float*)d_in[9],
      (float*)d_out);
}